// Round 8
// baseline (710.785 us; speedup 1.0000x reference)
//
#include <hip/hip_runtime.h>
#include <hip/hip_fp16.h>
#include <cstdint>
#include <cstddef>

// ---------------------------------------------------------------------------
// LightGCN on MI355X — direct-to-global CSR build + fp8(e4m3) Y-scaled storage.
//   Y-substitution: Y_l = diag(deg^-1/2) X_l => Y_{l+1} = (1/deg)*sum Y_l[c]
//     -> SpMM inner loop is a pure gather-sum.
//   fp8 OCP e4m3 Y storage (64 B rows), scaled by S=4096 (values ~1e-3 sit
//     in e4m3 normal range; S rides through the linear recursion, divided
//     out in gather_logits). R6 measured: spmm FETCH = 92 MB = cv 16 +
//     Y 76.8 (8-XCD compulsory floor), 43.8 us/layer, absmax 7e-7.
//   R8: CSR build rebuilt as 3 lean direct-to-global kernels (degree ->
//     rowptr -> scatter) using L2 global atomics; replaces the 2-phase
//     bucket-staged partition+finalize and its 32 MB tmp round-trip
//     (~96 MB -> ~48 MB build traffic, no BCAP capacity assumption).
//   SpMM mapping: 8 rows/wave, 8 lanes/row, 8 dims/lane (8 B/edge/lane);
//     8-edge batches, wave-max countable loop, cv prefetch regs.
//     Dummy edges gather row 0 (deg 0 -> Y[0,:]==0, L1-hot).
//   8 dispatches total.
// ---------------------------------------------------------------------------

typedef __attribute__((ext_vector_type(2))) float f32x2;

#define NB_SHIFT 8
#define YSCALE 4096.0f
#define YINV   (1.0f / 4096.0f)

// ---- pass 1: degrees + per-bucket totals (LDS hist -> bounded atomics) ----
__global__ __launch_bounds__(512) void degree_kernel(
    const int* __restrict__ rows, const int* __restrict__ cols,
    int* __restrict__ deg, int* __restrict__ bsum, int M, int nb) {
    __shared__ int lhist[1024];
    int t = threadIdx.x;
    for (int i = t; i < 1024; i += 512) lhist[i] = 0;
    __syncthreads();
    int full4 = M >> 2;
    const int4* r4 = (const int4*)rows;
    const int4* c4 = (const int4*)cols;
    for (int i4 = blockIdx.x * 512 + t; i4 < full4; i4 += gridDim.x * 512) {
        int4 u = r4[i4];
        int4 v = c4[i4];
        atomicAdd(&deg[u.x], 1); atomicAdd(&deg[u.y], 1);
        atomicAdd(&deg[u.z], 1); atomicAdd(&deg[u.w], 1);
        atomicAdd(&deg[v.x], 1); atomicAdd(&deg[v.y], 1);
        atomicAdd(&deg[v.z], 1); atomicAdd(&deg[v.w], 1);
        atomicAdd(&lhist[u.x >> NB_SHIFT], 1);
        atomicAdd(&lhist[u.y >> NB_SHIFT], 1);
        atomicAdd(&lhist[u.z >> NB_SHIFT], 1);
        atomicAdd(&lhist[u.w >> NB_SHIFT], 1);
        atomicAdd(&lhist[v.x >> NB_SHIFT], 1);
        atomicAdd(&lhist[v.y >> NB_SHIFT], 1);
        atomicAdd(&lhist[v.z >> NB_SHIFT], 1);
        atomicAdd(&lhist[v.w >> NB_SHIFT], 1);
    }
    if (blockIdx.x == 0) {
        int rem = M & 3;
        if (t < rem) {
            int u = rows[4 * full4 + t];
            int v = cols[4 * full4 + t];
            atomicAdd(&deg[u], 1);
            atomicAdd(&deg[v], 1);
            atomicAdd(&lhist[u >> NB_SHIFT], 1);
            atomicAdd(&lhist[v >> NB_SHIFT], 1);
        }
    }
    __syncthreads();
    for (int b = t; b < nb; b += 512) {
        int c = lhist[b];
        if (c) atomicAdd(&bsum[b], c);
    }
}

// ---- pass 2: row_ptr/cursor + dis/dis2/invd from deg + bsum ----
// 256-row buckets; cross-bucket base via self-computed prefix of bsum.
__global__ __launch_bounds__(256) void rowptr_kernel(
    const int* __restrict__ deg, const int* __restrict__ bsum,
    int* __restrict__ row_ptr, int* __restrict__ cursor,
    float* __restrict__ dis, float* __restrict__ dis2,
    float* __restrict__ invd, int n_nodes, int nb, int nnz) {
    __shared__ int wsum[4];
    __shared__ int red[256];
    int b = blockIdx.x;
    int t = threadIdx.x;
    int lane = t & 63, wv = t >> 6;
    // exclusive prefix of bsum over buckets < b
    int partial = 0;
    for (int i = t; i < b; i += 256) partial += bsum[i];
    red[t] = partial;
    __syncthreads();
    for (int off = 128; off > 0; off >>= 1) {
        if (t < off) red[t] += red[t + off];
        __syncthreads();
    }
    int dbeg = red[0];
    int row = (b << NB_SHIFT) + t;
    int v = (row < n_nodes) ? deg[row] : 0;
    int sc = v;
#pragma unroll
    for (int off = 1; off < 64; off <<= 1) {
        int x = __shfl_up(sc, off);
        if (lane >= off) sc += x;
    }
    if (lane == 63) wsum[wv] = sc;
    __syncthreads();
    int prefix = 0;
#pragma unroll
    for (int k = 0; k < 4; ++k) {
        int s = wsum[k];
        prefix += (k < wv) ? s : 0;
    }
    int ex = prefix + sc - v;
    if (row < n_nodes) {
        row_ptr[row] = dbeg + ex;
        cursor[row]  = dbeg + ex;
        double dv = (double)v;
        dis[row]  = (v > 0) ? (float)(1.0 / sqrt(dv)) : 0.0f;
        dis2[row] = (v > 0) ? (float)(1.0 / dv) : 0.0f;
        invd[row] = (v > 0) ? (float)sqrt(dv) : 0.0f;
    }
    if (b == nb - 1 && t == 0) row_ptr[n_nodes] = nnz;
}

// ---- pass 3: scatter mirror pairs into cv via per-row cursors ----
__global__ __launch_bounds__(512) void scatter_kernel(
    const int* __restrict__ rows, const int* __restrict__ cols,
    int* __restrict__ cursor, int* __restrict__ cv, int M) {
    int t = threadIdx.x;
    int full4 = M >> 2;
    const int4* r4 = (const int4*)rows;
    const int4* c4 = (const int4*)cols;
    for (int i4 = blockIdx.x * 512 + t; i4 < full4; i4 += gridDim.x * 512) {
        int4 u = r4[i4];
        int4 v = c4[i4];
        cv[atomicAdd(&cursor[u.x], 1)] = v.x;
        cv[atomicAdd(&cursor[v.x], 1)] = u.x;
        cv[atomicAdd(&cursor[u.y], 1)] = v.y;
        cv[atomicAdd(&cursor[v.y], 1)] = u.y;
        cv[atomicAdd(&cursor[u.z], 1)] = v.z;
        cv[atomicAdd(&cursor[v.z], 1)] = u.z;
        cv[atomicAdd(&cursor[u.w], 1)] = v.w;
        cv[atomicAdd(&cursor[v.w], 1)] = u.w;
    }
    if (blockIdx.x == 0) {
        int rem = M & 3;
        if (t < rem) {
            int u = rows[4 * full4 + t];
            int v = cols[4 * full4 + t];
            cv[atomicAdd(&cursor[u], 1)] = v;
            cv[atomicAdd(&cursor[v], 1)] = u;
        }
    }
}

// ---- streaming Y0 convert: Y0[row] = fp8(S * dis[row] * X0[row]) ----
// 64 B rows; one uint2 (8 dims) per thread.
__global__ __launch_bounds__(256) void convert_y0_kernel(
    const float4* __restrict__ ut4, const float4* __restrict__ it4,
    const float* __restrict__ dis, unsigned char* __restrict__ Y0,
    int usernum, int n_nodes) {
    int idx = blockIdx.x * 256 + threadIdx.x;
    int row = idx >> 3;
    if (row >= n_nodes) return;
    int c = idx & 7;          // 8 dims per thread: dims [8c, 8c+8)
    float d = dis[row] * YSCALE;
    const float4* srcp = (row <= usernum)
        ? (ut4 + (size_t)row * 16 + 2 * c)
        : (it4 + (size_t)(row - usernum) * 16 + 2 * c);
    float4 a = srcp[0];
    float4 e = srcp[1];
    int w0 = 0, w1 = 0;
    w0 = __builtin_amdgcn_cvt_pk_fp8_f32(d * a.x, d * a.y, w0, false);
    w0 = __builtin_amdgcn_cvt_pk_fp8_f32(d * a.z, d * a.w, w0, true);
    w1 = __builtin_amdgcn_cvt_pk_fp8_f32(d * e.x, d * e.y, w1, false);
    w1 = __builtin_amdgcn_cvt_pk_fp8_f32(d * e.z, d * e.w, w1, true);
    uint2 o;
    o.x = (unsigned)w0;
    o.y = (unsigned)w1;
    *(uint2*)(Y0 + (size_t)row * 64 + c * 8) = o;
}

__device__ inline int lane_dim(int g, int l8) {
    return l8 * 8 + ((g & 1) * 4 + (g & 2) + (g >> 2));
}

// ---- SpMM over fp8 Y: 8 rows/wave, 8 lanes/row, 8 dims/lane (8 B) ----
// Y_{l+1}[r][d] = dis2[r] * sum_e Y_l[cv[e]][d]   (values scaled by YSCALE)
// 8-edge batches, trip count = wave-max degree, cv prefetch regs.
// Out-of-range slots gather row 0 (deg 0 => Y[0,:]==0, L1-hot).
// cv must be readable ~8KB past nnz (padded); values masked before use.
__global__ __launch_bounds__(256) void spmm_y_kernel(
    const unsigned char* __restrict__ Yin, unsigned char* __restrict__ Yout,
    const int* __restrict__ row_ptr, const int* __restrict__ cv,
    const float* __restrict__ dis2, int n_nodes) {
    int wid  = (blockIdx.x * blockDim.x + threadIdx.x) >> 6;
    int lane = threadIdx.x & 63;
    int g = lane >> 3, sub = lane & 7;
    int row = wid * 8 + g;
    bool ok = row < n_nodes;
    int beg = 0, end = 0;
    if (ok) {
        beg = row_ptr[row];
        end = row_ptr[row + 1];
    }
    float d2 = ok ? dis2[row] : 0.0f;
    const char* Yb = (const char*)Yin;
    const char* cb = (const char*)cv;
    unsigned lo = (unsigned)sub * 8u;
    f32x2 a0 = {0.f, 0.f}, a1 = {0.f, 0.f}, a2 = {0.f, 0.f}, a3 = {0.f, 0.f};
    // wave-max degree -> uniform trip count
    int mx = end - beg;
    mx = max(mx, __shfl_xor(mx, 8));
    mx = max(mx, __shfl_xor(mx, 16));
    mx = max(mx, __shfl_xor(mx, 32));
    int iters = (mx + 7) >> 3;
    int j = beg;
    size_t jb = ((size_t)(unsigned)j) << 2;
    int r0 = *(const int*)(cb + jb);
    int r1 = *(const int*)(cb + jb + 4u);
    int r2 = *(const int*)(cb + jb + 8u);
    int r3 = *(const int*)(cb + jb + 12u);
    int r4 = *(const int*)(cb + jb + 16u);
    int r5 = *(const int*)(cb + jb + 20u);
    int r6 = *(const int*)(cb + jb + 24u);
    int r7 = *(const int*)(cb + jb + 28u);
    for (int it = 0; it < iters; ++it) {
        unsigned c0 = (unsigned)((j     < end) ? r0 : 0);
        unsigned c1 = (unsigned)((j + 1 < end) ? r1 : 0);
        unsigned c2 = (unsigned)((j + 2 < end) ? r2 : 0);
        unsigned c3 = (unsigned)((j + 3 < end) ? r3 : 0);
        unsigned c4 = (unsigned)((j + 4 < end) ? r4 : 0);
        unsigned c5 = (unsigned)((j + 5 < end) ? r5 : 0);
        unsigned c6 = (unsigned)((j + 6 < end) ? r6 : 0);
        unsigned c7 = (unsigned)((j + 7 < end) ? r7 : 0);
        uint2 q0 = *(const uint2*)(Yb + ((size_t)c0 << 6) + lo);
        uint2 q1 = *(const uint2*)(Yb + ((size_t)c1 << 6) + lo);
        uint2 q2 = *(const uint2*)(Yb + ((size_t)c2 << 6) + lo);
        uint2 q3 = *(const uint2*)(Yb + ((size_t)c3 << 6) + lo);
        uint2 q4 = *(const uint2*)(Yb + ((size_t)c4 << 6) + lo);
        uint2 q5 = *(const uint2*)(Yb + ((size_t)c5 << 6) + lo);
        uint2 q6 = *(const uint2*)(Yb + ((size_t)c6 << 6) + lo);
        uint2 q7 = *(const uint2*)(Yb + ((size_t)c7 << 6) + lo);
        // prefetch next batch's indices (pad-safe past nnz; masked above)
        j += 8;
        jb = ((size_t)(unsigned)j) << 2;
        r0 = *(const int*)(cb + jb);
        r1 = *(const int*)(cb + jb + 4u);
        r2 = *(const int*)(cb + jb + 8u);
        r3 = *(const int*)(cb + jb + 12u);
        r4 = *(const int*)(cb + jb + 16u);
        r5 = *(const int*)(cb + jb + 20u);
        r6 = *(const int*)(cb + jb + 24u);
        r7 = *(const int*)(cb + jb + 28u);
        // HW fp8 decode (2 dims/cvt) + packed f32 adds
#define ACC_EDGE(q)                                                  \
        a0 += __builtin_amdgcn_cvt_pk_f32_fp8((q).x, false);         \
        a1 += __builtin_amdgcn_cvt_pk_f32_fp8((q).x, true);          \
        a2 += __builtin_amdgcn_cvt_pk_f32_fp8((q).y, false);         \
        a3 += __builtin_amdgcn_cvt_pk_f32_fp8((q).y, true);
        ACC_EDGE(q0) ACC_EDGE(q1) ACC_EDGE(q2) ACC_EDGE(q3)
        ACC_EDGE(q4) ACC_EDGE(q5) ACC_EDGE(q6) ACC_EDGE(q7)
#undef ACC_EDGE
    }
    if (ok) {
        int w0 = 0, w1 = 0;
        w0 = __builtin_amdgcn_cvt_pk_fp8_f32(a0.x * d2, a0.y * d2, w0, false);
        w0 = __builtin_amdgcn_cvt_pk_fp8_f32(a1.x * d2, a1.y * d2, w0, true);
        w1 = __builtin_amdgcn_cvt_pk_fp8_f32(a2.x * d2, a2.y * d2, w1, false);
        w1 = __builtin_amdgcn_cvt_pk_fp8_f32(a3.x * d2, a3.y * d2, w1, true);
        uint2 o;
        o.x = (unsigned)w0;
        o.y = (unsigned)w1;
        *(uint2*)(Yout + (size_t)row * 64 + lo) = o;
    }
}

// fused layer-3 + gather + logits: one wave per batch element.
// The 3 CSR row-sums (u, pos, neg) run in ONE interleaved loop —
// 3 gather chains overlap instead of concatenating. Exhausted rows gather
// row 0 (Y[0,:]==0, L1-hot). Trip count is wave-uniform (all lanes share w).
// emb(idx)[d] = X0fp32[idx][d] + invd*(Y1+Y2)[idx][d]/S + rowdot(Y2)[d]*dis/S
// out[b] = <emb(u), emb(pos)>/16; out[B+b] = <emb(u), emb(neg)>/16.
__global__ __launch_bounds__(256) void gather_logits_kernel(
    const float* __restrict__ ut, const float* __restrict__ itb,
    const unsigned char* __restrict__ Y1, const unsigned char* __restrict__ Y2,
    const int* __restrict__ row_ptr, const int* __restrict__ cv,
    const float* __restrict__ dis, const float* __restrict__ invd,
    const int* __restrict__ user_ids, const int* __restrict__ pos_seqs,
    const int* __restrict__ neg_seqs, float* __restrict__ out,
    int usernum, int itemnum, int batch) {
    int w    = (blockIdx.x * blockDim.x + threadIdx.x) >> 6;
    int lane = threadIdx.x & 63;
    if (w >= batch) return;
    int g = lane >> 3, l8 = lane & 7;
    int d = lane_dim(g, l8);
    int idxs[3];
    int u = min(max(user_ids[w], 0), usernum);
    idxs[0] = u;
    int p = min(max(pos_seqs[w], 1), itemnum);
    idxs[1] = usernum + p;
    int nn = min(max(neg_seqs[w], 1), itemnum);
    idxs[2] = usernum + nn;
    int beg0 = row_ptr[idxs[0]], end0 = row_ptr[idxs[0] + 1];
    int beg1 = row_ptr[idxs[1]], end1 = row_ptr[idxs[1] + 1];
    int beg2 = row_ptr[idxs[2]], end2 = row_ptr[idxs[2] + 1];
    int mx = max(end0 - beg0, max(end1 - beg1, end2 - beg2));
    int iters = (mx + 7) >> 3;
    const char* Yb = (const char*)Y2;
    const char* cb = (const char*)cv;
    unsigned lo = (unsigned)l8 * 8u;
    // 3 rows x 8-dim accumulators (f32x2 x4 each)
    f32x2 A00 = {0.f,0.f}, A01 = {0.f,0.f}, A02 = {0.f,0.f}, A03 = {0.f,0.f};
    f32x2 A10 = {0.f,0.f}, A11 = {0.f,0.f}, A12 = {0.f,0.f}, A13 = {0.f,0.f};
    f32x2 A20 = {0.f,0.f}, A21 = {0.f,0.f}, A22 = {0.f,0.f}, A23 = {0.f,0.f};
    int j0 = beg0 + g, j1 = beg1 + g, j2 = beg2 + g;
    for (int it = 0; it < iters; ++it) {
        // cv loads for all 3 rows (pad-safe past nnz; masked before gather)
        int r0 = *(const int*)(cb + (((size_t)(unsigned)j0) << 2));
        int r1 = *(const int*)(cb + (((size_t)(unsigned)j1) << 2));
        int r2 = *(const int*)(cb + (((size_t)(unsigned)j2) << 2));
        unsigned c0 = (unsigned)((j0 < end0) ? r0 : 0);
        unsigned c1 = (unsigned)((j1 < end1) ? r1 : 0);
        unsigned c2 = (unsigned)((j2 < end2) ? r2 : 0);
        uint2 q0 = *(const uint2*)(Yb + ((size_t)c0 << 6) + lo);
        uint2 q1 = *(const uint2*)(Yb + ((size_t)c1 << 6) + lo);
        uint2 q2 = *(const uint2*)(Yb + ((size_t)c2 << 6) + lo);
        A00 += __builtin_amdgcn_cvt_pk_f32_fp8(q0.x, false);
        A01 += __builtin_amdgcn_cvt_pk_f32_fp8(q0.x, true);
        A02 += __builtin_amdgcn_cvt_pk_f32_fp8(q0.y, false);
        A03 += __builtin_amdgcn_cvt_pk_f32_fp8(q0.y, true);
        A10 += __builtin_amdgcn_cvt_pk_f32_fp8(q1.x, false);
        A11 += __builtin_amdgcn_cvt_pk_f32_fp8(q1.x, true);
        A12 += __builtin_amdgcn_cvt_pk_f32_fp8(q1.y, false);
        A13 += __builtin_amdgcn_cvt_pk_f32_fp8(q1.y, true);
        A20 += __builtin_amdgcn_cvt_pk_f32_fp8(q2.x, false);
        A21 += __builtin_amdgcn_cvt_pk_f32_fp8(q2.x, true);
        A22 += __builtin_amdgcn_cvt_pk_f32_fp8(q2.y, false);
        A23 += __builtin_amdgcn_cvt_pk_f32_fp8(q2.y, true);
        j0 += 8; j1 += 8; j2 += 8;
    }
    // butterfly each row's 8 partials down to one dim per lane
    float fins[3];
#pragma unroll
    for (int q = 0; q < 3; ++q) {
        f32x2 b0q, b1q, b2q, b3q;
        if (q == 0) { b0q = A00; b1q = A01; b2q = A02; b3q = A03; }
        else if (q == 1) { b0q = A10; b1q = A11; b2q = A12; b3q = A13; }
        else { b0q = A20; b1q = A21; b2q = A22; b3q = A23; }
        float acc[8] = {b0q.x, b0q.y, b1q.x, b1q.y,
                        b2q.x, b2q.y, b3q.x, b3q.y};
        bool gb0 = (g & 1) != 0;
        bool gb1 = (g & 2) != 0;
        bool gb2 = (g & 4) != 0;
        float s0 = gb0 ? acc[0] : acc[4];
        float s1 = gb0 ? acc[1] : acc[5];
        float s2 = gb0 ? acc[2] : acc[6];
        float s3 = gb0 ? acc[3] : acc[7];
        float a0f = (gb0 ? acc[4] : acc[0]) + __shfl_xor(s0, 8);
        float a1f = (gb0 ? acc[5] : acc[1]) + __shfl_xor(s1, 8);
        float a2f = (gb0 ? acc[6] : acc[2]) + __shfl_xor(s2, 8);
        float a3f = (gb0 ? acc[7] : acc[3]) + __shfl_xor(s3, 8);
        float t0 = gb1 ? a0f : a2f;
        float t1 = gb1 ? a1f : a3f;
        float c0f = (gb1 ? a2f : a0f) + __shfl_xor(t0, 16);
        float c1f = (gb1 ? a3f : a1f) + __shfl_xor(t1, 16);
        float uu = gb2 ? c0f : c1f;
        fins[q] = (gb2 ? c1f : c0f) + __shfl_xor(uu, 32);
    }
    float vals[3];
#pragma unroll
    for (int q = 0; q < 3; ++q) {
        int idx = idxs[q];
        float dr = dis[idx] * YINV;
        float iv = invd[idx] * YINV;
        const float* base0 = (q == 0) ? (ut + (size_t)u * 64)
                                      : (itb + (size_t)(idx - usernum) * 64);
        float x0v = base0[d];
        int b1 = (int)Y1[(size_t)idx * 64 + d];
        int b2 = (int)Y2[(size_t)idx * 64 + d];
        float y1v = __builtin_amdgcn_cvt_f32_fp8(b1, 0);
        float y2v = __builtin_amdgcn_cvt_f32_fp8(b2, 0);
        vals[q] = x0v + iv * (y1v + y2v) + fins[q] * dr;
    }
    float dp = vals[0] * vals[1];
    float dn = vals[0] * vals[2];
#pragma unroll
    for (int off = 1; off < 64; off <<= 1) {
        dp += __shfl_xor(dp, off);
        dn += __shfl_xor(dn, off);
    }
    if (lane == 0) {
        out[w]         = dp * 0.0625f;
        out[batch + w] = dn * 0.0625f;
    }
}

extern "C" void kernel_launch(void* const* d_in, const int* in_sizes, int n_in,
                              void* d_out, int out_size, void* d_ws,
                              size_t ws_size, hipStream_t stream) {
    const float* user_table = (const float*)d_in[0];
    const float* item_table = (const float*)d_in[1];
    const int*   rows       = (const int*)d_in[3];
    const int*   cols       = (const int*)d_in[4];
    const int*   user_ids   = (const int*)d_in[5];
    const int*   pos_seqs   = (const int*)d_in[6];
    const int*   neg_seqs   = (const int*)d_in[7];
    float*       out        = (float*)d_out;

    const int D = 64;
    int usernum = in_sizes[0] / D - 1;   // 100000
    int itemnum = in_sizes[1] / D - 1;   // 50000
    int nnz     = in_sizes[2];           // 4,000,000
    int batch   = in_sizes[5];           // 4096
    int n_nodes = usernum + itemnum + 1; // 150001
    int nb      = (n_nodes + (1 << NB_SHIFT) - 1) >> NB_SHIFT;  // 586
    int M       = nnz >> 1;              // 2,000,000 source pairs (mirror COO)

    // ---- workspace layout ----
    char* w = (char*)d_ws;
    auto alloc = [&](size_t bytes) {
        char* p = w;
        w += (bytes + 255) & ~(size_t)255;
        return p;
    };
    size_t ysz = (size_t)n_nodes * 64;          // 9.6 MB per fp8 Y buffer
    unsigned char* Y0 = (unsigned char*)alloc(ysz);
    unsigned char* Y1 = (unsigned char*)alloc(ysz);
    unsigned char* Y2 = (unsigned char*)alloc(ysz);
    int*   cv       = (int*)alloc((size_t)nnz * 4 + 8192);  // +pad: gather
                                      // loops may read cv past nnz; values
                                      // are masked before use as addresses
    int*   row_ptr  = (int*)alloc((size_t)(n_nodes + 1) * 4);
    int*   cursor   = (int*)alloc((size_t)n_nodes * 4);
    int*   degbuf   = (int*)alloc((size_t)(n_nodes + 1024) * 4);
    int*   deg      = degbuf;
    int*   bsum     = degbuf + n_nodes;
    float* dis      = (float*)alloc((size_t)n_nodes * 4);
    float* dis2     = (float*)alloc((size_t)n_nodes * 4);
    float* invd     = (float*)alloc((size_t)n_nodes * 4);

    // ---- CSR build: degree -> rowptr -> scatter (direct, no staging) ----
    hipMemsetAsync(degbuf, 0, (size_t)(n_nodes + 1024) * 4, stream);
    degree_kernel<<<512, 512, 0, stream>>>(rows, cols, deg, bsum, M, nb);
    rowptr_kernel<<<nb, 256, 0, stream>>>(deg, bsum, row_ptr, cursor, dis,
                                          dis2, invd, n_nodes, nb, nnz);
    scatter_kernel<<<512, 512, 0, stream>>>(rows, cols, cursor, cv, M);

    // ---- Y0 convert ----
    int conv_blocks = (n_nodes * 8 + 255) / 256;
    convert_y0_kernel<<<conv_blocks, 256, 0, stream>>>(
        (const float4*)user_table, (const float4*)item_table, dis,
        Y0, usernum, n_nodes);

    // ---- layers: Y0 -> Y1 -> Y2 (fp8 gather-sum + 1/deg scale) ----
    int spmm_grid = (n_nodes + 31) / 32;   // 32 rows per 256-thr block
    spmm_y_kernel<<<spmm_grid, 256, 0, stream>>>(Y0, Y1, row_ptr, cv, dis2,
                                                 n_nodes);
    spmm_y_kernel<<<spmm_grid, 256, 0, stream>>>(Y1, Y2, row_ptr, cv, dis2,
                                                 n_nodes);

    // ---- fused layer-3 + gather + logits ----
    gather_logits_kernel<<<(batch + 3) / 4, 256, 0, stream>>>(
        user_table, item_table, Y1, Y2, row_ptr, cv, dis, invd, user_ids,
        pos_seqs, neg_seqs, out, usernum, itemnum, batch);
}

// Round 9
// 600.179 us; speedup vs baseline: 1.1843x; 1.1843x over previous
//
#include <hip/hip_runtime.h>
#include <hip/hip_fp16.h>
#include <cstdint>
#include <cstddef>

// ---------------------------------------------------------------------------
// LightGCN on MI355X — bucket-staged CSR build + fp8(e4m3) Y-scaled storage.
//   Y-substitution: Y_l = diag(deg^-1/2) X_l => Y_{l+1} = (1/deg)*sum Y_l[c]
//     -> SpMM inner loop is a pure gather-sum.
//   fp8 OCP e4m3 Y storage (64 B rows), scaled by S=4096 (values ~1e-3 sit
//     in e4m3 normal range; S rides through the linear recursion, divided
//     out in gather_logits). Measured: spmm FETCH = 92 MB = cv 16 + Y 76.8
//     (8-XCD compulsory floor), absmax 7e-7.
//   R9: build REVERTED to the R7 bucket-staged partition+finalize (R8's
//     direct global-atomic build measured 240-350 us/kernel — per-edge
//     atomics-with-return + scattered dword stores are ~25x slower than
//     LDS-staged; lesson recorded). NEW: degree-binned row permutation —
//     finalize histograms exact degrees (128 bins), perm_kernel groups
//     equal-degree rows; spmm processes perm[slot] so all 8 rows of a wave
//     share one degree -> wave-max tail waste 27% -> ~2%. Per-row
//     arithmetic unchanged -> bitwise-identical output.
//   8 dispatches total.
// ---------------------------------------------------------------------------

typedef __attribute__((ext_vector_type(2))) float f32x2;

#define NB_SHIFT 8
#define BCAP 16000      // max edges per 256-row bucket (expected max ~10.7K)
#define P1_SRC 4096     // source pairs per tile -> 8192 directed edges
#define P1_DIM 512
#define YSCALE 4096.0f
#define YINV   (1.0f / 4096.0f)

// ---- partition mirror pairs into fixed-capacity bucket regions ----
__global__ __launch_bounds__(P1_DIM) void partition_kernel(
    const int* __restrict__ rows, const int* __restrict__ cols,
    int* __restrict__ bucket_cursor, int* __restrict__ tmp,
    int M /* = nnz/2 */, int nb) {
    __shared__ int            lhist[1024];
    __shared__ int            loff[1024];
    __shared__ int            ldelta[1024];   // dest_base[b] - loff[b]
    __shared__ int            wsum[8];
    __shared__ int            stage[2 * P1_SRC];   // 32 KB
    __shared__ unsigned short bstage[2 * P1_SRC];  // 16 KB
    int t = threadIdx.x;
    int lane = t & 63, wv = t >> 6;
    int base     = blockIdx.x * P1_SRC;
    int cnt_here = min(P1_SRC, M - base);
    int full4    = cnt_here >> 2;
    int rem      = cnt_here & 3;
    for (int i = t; i < 1024; i += P1_DIM) lhist[i] = 0;
    __syncthreads();
    const int4* rows4 = (const int4*)(rows + base);
    const int4* cols4 = (const int4*)(cols + base);
    int4 uu[2], vv[2];
    int  rka[8], rkb[8];
#pragma unroll
    for (int k = 0; k < 2; ++k) {
        int i4 = t + k * P1_DIM;
        if (i4 < full4) {
            uu[k] = rows4[i4];
            vv[k] = cols4[i4];
            int u4[4] = {uu[k].x, uu[k].y, uu[k].z, uu[k].w};
            int v4[4] = {vv[k].x, vv[k].y, vv[k].z, vv[k].w};
#pragma unroll
            for (int e = 0; e < 4; ++e) {
                rka[4 * k + e] = atomicAdd(&lhist[u4[e] >> NB_SHIFT], 1);
                rkb[4 * k + e] = atomicAdd(&lhist[v4[e] >> NB_SHIFT], 1);
            }
        }
    }
    int ur = 0, vr = 0, rkra = 0, rkrb = 0;
    bool has_rem = (t < rem);
    if (has_rem) {
        ur = rows[base + 4 * full4 + t];
        vr = cols[base + 4 * full4 + t];
        rkra = atomicAdd(&lhist[ur >> NB_SHIFT], 1);
        rkrb = atomicAdd(&lhist[vr >> NB_SHIFT], 1);
    }
    __syncthreads();
    // wave-shuffle exclusive scan over 1024 bucket counts (2 per thread)
    int v0 = lhist[2 * t], v1 = lhist[2 * t + 1];
    int ts = v0 + v1;
    int sc = ts;
#pragma unroll
    for (int off = 1; off < 64; off <<= 1) {
        int x = __shfl_up(sc, off);
        if (lane >= off) sc += x;
    }
    if (lane == 63) wsum[wv] = sc;
    __syncthreads();
    int prefix = 0;
#pragma unroll
    for (int k = 0; k < 8; ++k) {
        int s = wsum[k];
        prefix += (k < wv) ? s : 0;
    }
    int run = prefix + sc - ts;  // exclusive prefix of ts
    loff[2 * t]     = run;
    loff[2 * t + 1] = run + v0;
#pragma unroll
    for (int k = 0; k < 2; ++k) {
        int b  = 2 * t + k;
        int vvk = (k == 0) ? v0 : v1;
        if (b < nb && vvk > 0) {
            int old = atomicAdd(&bucket_cursor[b], vvk);   // delta in bucket
            ldelta[b] = b * BCAP + old - loff[b];
        }
    }
    __syncthreads();
#pragma unroll
    for (int k = 0; k < 2; ++k) {
        int i4 = t + k * P1_DIM;
        if (i4 < full4) {
            int u4[4] = {uu[k].x, uu[k].y, uu[k].z, uu[k].w};
            int v4[4] = {vv[k].x, vv[k].y, vv[k].z, vv[k].w};
#pragma unroll
            for (int e = 0; e < 4; ++e) {
                int ub = u4[e] >> NB_SHIFT;
                int s1 = loff[ub] + rka[4 * k + e];
                stage[s1]  = ((u4[e] & 255) << 18) | v4[e];
                bstage[s1] = (unsigned short)ub;
                int vb = v4[e] >> NB_SHIFT;
                int s2 = loff[vb] + rkb[4 * k + e];
                stage[s2]  = ((v4[e] & 255) << 18) | u4[e];
                bstage[s2] = (unsigned short)vb;
            }
        }
    }
    if (has_rem) {
        int ub = ur >> NB_SHIFT;
        int s1 = loff[ub] + rkra;
        stage[s1]  = ((ur & 255) << 18) | vr;
        bstage[s1] = (unsigned short)ub;
        int vb = vr >> NB_SHIFT;
        int s2 = loff[vb] + rkrb;
        stage[s2]  = ((vr & 255) << 18) | ur;
        bstage[s2] = (unsigned short)vb;
    }
    __syncthreads();
    int total = 2 * cnt_here;
    for (int s = t; s < total; s += P1_DIM) {
        tmp[s + ldelta[bstage[s]]] = stage[s];
    }
}

// ---- per-bucket finalize: self-prefix, row_ptr, dis/dis2/invd, cv ----
// + R9: exact-degree histogram (128 bins) + deg output for perm_kernel.
__global__ __launch_bounds__(512) void finalize_kernel(
    const int* __restrict__ tmp, const int* __restrict__ bcur,
    int* __restrict__ row_ptr, float* __restrict__ dis,
    float* __restrict__ dis2, float* __restrict__ invd,
    int* __restrict__ cv, int* __restrict__ deg_out,
    int* __restrict__ dhist, int n_nodes, int nb, int nnz) {
    __shared__ int rcnt[256];
    __shared__ int ccur[256];   // global write cursor per row
    __shared__ int wsum[4];
    __shared__ int red[512];
    int b = blockIdx.x;
    int t = threadIdx.x;
    int lane = t & 63, wv = t >> 6;
    // exclusive prefix of bcur over buckets < b
    int partial = 0;
    for (int i = t; i < b; i += 512) partial += bcur[i];
    red[t] = partial;
    __syncthreads();
    for (int off = 256; off > 0; off >>= 1) {
        if (t < off) red[t] += red[t + off];
        __syncthreads();
    }
    int dbeg  = red[0];
    int count = bcur[b];
    int src   = b * BCAP;
    if (t < 256) rcnt[t] = 0;
    __syncthreads();
    for (int i = t; i < count; i += 512) {
        atomicAdd(&rcnt[tmp[src + i] >> 18], 1);
    }
    __syncthreads();
    // scan over 256 row counts (waves 0..3 fully active -> safe shuffles)
    int v = 0, sc = 0;
    if (t < 256) {
        v  = rcnt[t];
        sc = v;
#pragma unroll
        for (int off = 1; off < 64; off <<= 1) {
            int x = __shfl_up(sc, off);
            if (lane >= off) sc += x;
        }
        if (lane == 63) wsum[wv] = sc;
    }
    __syncthreads();
    if (t < 256) {
        int prefix = 0;
#pragma unroll
        for (int k = 0; k < 4; ++k) {
            int s = wsum[k];
            prefix += (k < wv) ? s : 0;
        }
        int ex = prefix + sc - v;
        ccur[t] = dbeg + ex;       // global cursor -> rank writes direct
        int row = (b << NB_SHIFT) + t;
        if (row < n_nodes) {
            row_ptr[row] = dbeg + ex;
            deg_out[row] = v;
            atomicAdd(&dhist[v < 127 ? v : 127], 1);
            double dv = (double)v;
            dis[row]  = (v > 0) ? (float)(1.0 / sqrt(dv)) : 0.0f;
            dis2[row] = (v > 0) ? (float)(1.0 / dv) : 0.0f;
            invd[row] = (v > 0) ? (float)sqrt(dv) : 0.0f;
        }
    }
    if (b == nb - 1 && t == 0) row_ptr[n_nodes] = nnz;
    __syncthreads();
    // rank + direct cv write: dest window ~28KB -> L2 write-merge
    for (int i = t; i < count; i += 512) {
        int p  = tmp[src + i];
        int rk = atomicAdd(&ccur[p >> 18], 1);
        cv[rk] = p & 0x3FFFF;
    }
}

// ---- degree-binned permutation: perm groups equal-degree rows ----
// Two-level rank (LDS rank + one bounded global atomic per (block,bin)) —
// NOT per-edge global atomics (R8 lesson). Each block handles 256 rows.
__global__ __launch_bounds__(256) void perm_kernel(
    const int* __restrict__ deg, const int* __restrict__ dhist,
    int* __restrict__ dcur, int* __restrict__ perm, int n_nodes) {
    __shared__ int dh[128];
    __shared__ int base[128];
    __shared__ int lhist[128];
    __shared__ int lcur[128];
    __shared__ int bbase[128];
    int t = threadIdx.x;
    if (t < 128) {
        dh[t]    = dhist[t];
        lhist[t] = 0;
        lcur[t]  = 0;
    }
    __syncthreads();
    if (t == 0) {
        int run = 0;
        for (int b = 0; b < 128; ++b) { base[b] = run; run += dh[b]; }
    }
    int row = blockIdx.x * 256 + t;
    int bin = -1;
    if (row < n_nodes) {
        int v = deg[row];
        bin = v < 127 ? v : 127;
        atomicAdd(&lhist[bin], 1);
    }
    __syncthreads();
    if (t < 128) {
        int c = lhist[t];
        bbase[t] = c ? atomicAdd(&dcur[t], c) : 0;
    }
    __syncthreads();
    if (row < n_nodes) {
        int r = atomicAdd(&lcur[bin], 1);
        perm[base[bin] + bbase[bin] + r] = row;
    }
}

// ---- streaming Y0 convert: Y0[row] = fp8(S * dis[row] * X0[row]) ----
// 64 B rows; one uint2 (8 dims) per thread.
__global__ __launch_bounds__(256) void convert_y0_kernel(
    const float4* __restrict__ ut4, const float4* __restrict__ it4,
    const float* __restrict__ dis, unsigned char* __restrict__ Y0,
    int usernum, int n_nodes) {
    int idx = blockIdx.x * 256 + threadIdx.x;
    int row = idx >> 3;
    if (row >= n_nodes) return;
    int c = idx & 7;          // 8 dims per thread: dims [8c, 8c+8)
    float d = dis[row] * YSCALE;
    const float4* srcp = (row <= usernum)
        ? (ut4 + (size_t)row * 16 + 2 * c)
        : (it4 + (size_t)(row - usernum) * 16 + 2 * c);
    float4 a = srcp[0];
    float4 e = srcp[1];
    int w0 = 0, w1 = 0;
    w0 = __builtin_amdgcn_cvt_pk_fp8_f32(d * a.x, d * a.y, w0, false);
    w0 = __builtin_amdgcn_cvt_pk_fp8_f32(d * a.z, d * a.w, w0, true);
    w1 = __builtin_amdgcn_cvt_pk_fp8_f32(d * e.x, d * e.y, w1, false);
    w1 = __builtin_amdgcn_cvt_pk_fp8_f32(d * e.z, d * e.w, w1, true);
    uint2 o;
    o.x = (unsigned)w0;
    o.y = (unsigned)w1;
    *(uint2*)(Y0 + (size_t)row * 64 + c * 8) = o;
}

__device__ inline int lane_dim(int g, int l8) {
    return l8 * 8 + ((g & 1) * 4 + (g & 2) + (g >> 2));
}

// ---- SpMM over fp8 Y: 8 rows/wave, 8 lanes/row, 8 dims/lane (8 B) ----
// Y_{l+1}[r][d] = dis2[r] * sum_e Y_l[cv[e]][d]   (values scaled by YSCALE)
// R9: rows taken via degree-binned perm -> all 8 rows of a wave share one
// degree -> wave-max trip count ~= per-row trip count (tail waste ~2%).
// 8-edge batches, cv prefetch regs. Out-of-range slots gather row 0
// (deg 0 => Y[0,:]==0, L1-hot). cv padded ~8KB past nnz; masked before use.
__global__ __launch_bounds__(256) void spmm_y_kernel(
    const unsigned char* __restrict__ Yin, unsigned char* __restrict__ Yout,
    const int* __restrict__ row_ptr, const int* __restrict__ cv,
    const float* __restrict__ dis2, const int* __restrict__ perm,
    int n_nodes) {
    int wid  = (blockIdx.x * blockDim.x + threadIdx.x) >> 6;
    int lane = threadIdx.x & 63;
    int g = lane >> 3, sub = lane & 7;
    int slot = wid * 8 + g;
    bool ok = slot < n_nodes;
    int row = ok ? perm[slot] : 0;
    int beg = 0, end = 0;
    if (ok) {
        beg = row_ptr[row];
        end = row_ptr[row + 1];
    }
    float d2 = ok ? dis2[row] : 0.0f;
    const char* Yb = (const char*)Yin;
    const char* cb = (const char*)cv;
    unsigned lo = (unsigned)sub * 8u;
    f32x2 a0 = {0.f, 0.f}, a1 = {0.f, 0.f}, a2 = {0.f, 0.f}, a3 = {0.f, 0.f};
    // wave-max degree -> uniform trip count (equal-degree rows: tight)
    int mx = end - beg;
    mx = max(mx, __shfl_xor(mx, 8));
    mx = max(mx, __shfl_xor(mx, 16));
    mx = max(mx, __shfl_xor(mx, 32));
    int iters = (mx + 7) >> 3;
    int j = beg;
    size_t jb = ((size_t)(unsigned)j) << 2;
    int r0 = *(const int*)(cb + jb);
    int r1 = *(const int*)(cb + jb + 4u);
    int r2 = *(const int*)(cb + jb + 8u);
    int r3 = *(const int*)(cb + jb + 12u);
    int r4 = *(const int*)(cb + jb + 16u);
    int r5 = *(const int*)(cb + jb + 20u);
    int r6 = *(const int*)(cb + jb + 24u);
    int r7 = *(const int*)(cb + jb + 28u);
    for (int it = 0; it < iters; ++it) {
        unsigned c0 = (unsigned)((j     < end) ? r0 : 0);
        unsigned c1 = (unsigned)((j + 1 < end) ? r1 : 0);
        unsigned c2 = (unsigned)((j + 2 < end) ? r2 : 0);
        unsigned c3 = (unsigned)((j + 3 < end) ? r3 : 0);
        unsigned c4 = (unsigned)((j + 4 < end) ? r4 : 0);
        unsigned c5 = (unsigned)((j + 5 < end) ? r5 : 0);
        unsigned c6 = (unsigned)((j + 6 < end) ? r6 : 0);
        unsigned c7 = (unsigned)((j + 7 < end) ? r7 : 0);
        uint2 q0 = *(const uint2*)(Yb + ((size_t)c0 << 6) + lo);
        uint2 q1 = *(const uint2*)(Yb + ((size_t)c1 << 6) + lo);
        uint2 q2 = *(const uint2*)(Yb + ((size_t)c2 << 6) + lo);
        uint2 q3 = *(const uint2*)(Yb + ((size_t)c3 << 6) + lo);
        uint2 q4 = *(const uint2*)(Yb + ((size_t)c4 << 6) + lo);
        uint2 q5 = *(const uint2*)(Yb + ((size_t)c5 << 6) + lo);
        uint2 q6 = *(const uint2*)(Yb + ((size_t)c6 << 6) + lo);
        uint2 q7 = *(const uint2*)(Yb + ((size_t)c7 << 6) + lo);
        // prefetch next batch's indices (pad-safe past nnz; masked above)
        j += 8;
        jb = ((size_t)(unsigned)j) << 2;
        r0 = *(const int*)(cb + jb);
        r1 = *(const int*)(cb + jb + 4u);
        r2 = *(const int*)(cb + jb + 8u);
        r3 = *(const int*)(cb + jb + 12u);
        r4 = *(const int*)(cb + jb + 16u);
        r5 = *(const int*)(cb + jb + 20u);
        r6 = *(const int*)(cb + jb + 24u);
        r7 = *(const int*)(cb + jb + 28u);
        // HW fp8 decode (2 dims/cvt) + packed f32 adds
#define ACC_EDGE(q)                                                  \
        a0 += __builtin_amdgcn_cvt_pk_f32_fp8((q).x, false);         \
        a1 += __builtin_amdgcn_cvt_pk_f32_fp8((q).x, true);          \
        a2 += __builtin_amdgcn_cvt_pk_f32_fp8((q).y, false);         \
        a3 += __builtin_amdgcn_cvt_pk_f32_fp8((q).y, true);
        ACC_EDGE(q0) ACC_EDGE(q1) ACC_EDGE(q2) ACC_EDGE(q3)
        ACC_EDGE(q4) ACC_EDGE(q5) ACC_EDGE(q6) ACC_EDGE(q7)
#undef ACC_EDGE
    }
    if (ok) {
        int w0 = 0, w1 = 0;
        w0 = __builtin_amdgcn_cvt_pk_fp8_f32(a0.x * d2, a0.y * d2, w0, false);
        w0 = __builtin_amdgcn_cvt_pk_fp8_f32(a1.x * d2, a1.y * d2, w0, true);
        w1 = __builtin_amdgcn_cvt_pk_fp8_f32(a2.x * d2, a2.y * d2, w1, false);
        w1 = __builtin_amdgcn_cvt_pk_fp8_f32(a3.x * d2, a3.y * d2, w1, true);
        uint2 o;
        o.x = (unsigned)w0;
        o.y = (unsigned)w1;
        *(uint2*)(Yout + (size_t)row * 64 + lo) = o;
    }
}

// fused layer-3 + gather + logits: one wave per batch element.
// The 3 CSR row-sums (u, pos, neg) run in ONE interleaved loop —
// 3 gather chains overlap instead of concatenating. Exhausted rows gather
// row 0 (Y[0,:]==0, L1-hot). Trip count is wave-uniform (all lanes share w).
// emb(idx)[d] = X0fp32[idx][d] + invd*(Y1+Y2)[idx][d]/S + rowdot(Y2)[d]*dis/S
// out[b] = <emb(u), emb(pos)>/16; out[B+b] = <emb(u), emb(neg)>/16.
__global__ __launch_bounds__(256) void gather_logits_kernel(
    const float* __restrict__ ut, const float* __restrict__ itb,
    const unsigned char* __restrict__ Y1, const unsigned char* __restrict__ Y2,
    const int* __restrict__ row_ptr, const int* __restrict__ cv,
    const float* __restrict__ dis, const float* __restrict__ invd,
    const int* __restrict__ user_ids, const int* __restrict__ pos_seqs,
    const int* __restrict__ neg_seqs, float* __restrict__ out,
    int usernum, int itemnum, int batch) {
    int w    = (blockIdx.x * blockDim.x + threadIdx.x) >> 6;
    int lane = threadIdx.x & 63;
    if (w >= batch) return;
    int g = lane >> 3, l8 = lane & 7;
    int d = lane_dim(g, l8);
    int idxs[3];
    int u = min(max(user_ids[w], 0), usernum);
    idxs[0] = u;
    int p = min(max(pos_seqs[w], 1), itemnum);
    idxs[1] = usernum + p;
    int nn = min(max(neg_seqs[w], 1), itemnum);
    idxs[2] = usernum + nn;
    int beg0 = row_ptr[idxs[0]], end0 = row_ptr[idxs[0] + 1];
    int beg1 = row_ptr[idxs[1]], end1 = row_ptr[idxs[1] + 1];
    int beg2 = row_ptr[idxs[2]], end2 = row_ptr[idxs[2] + 1];
    int mx = max(end0 - beg0, max(end1 - beg1, end2 - beg2));
    int iters = (mx + 7) >> 3;
    const char* Yb = (const char*)Y2;
    const char* cb = (const char*)cv;
    unsigned lo = (unsigned)l8 * 8u;
    // 3 rows x 8-dim accumulators (f32x2 x4 each)
    f32x2 A00 = {0.f,0.f}, A01 = {0.f,0.f}, A02 = {0.f,0.f}, A03 = {0.f,0.f};
    f32x2 A10 = {0.f,0.f}, A11 = {0.f,0.f}, A12 = {0.f,0.f}, A13 = {0.f,0.f};
    f32x2 A20 = {0.f,0.f}, A21 = {0.f,0.f}, A22 = {0.f,0.f}, A23 = {0.f,0.f};
    int j0 = beg0 + g, j1 = beg1 + g, j2 = beg2 + g;
    for (int it = 0; it < iters; ++it) {
        // cv loads for all 3 rows (pad-safe past nnz; masked before gather)
        int r0 = *(const int*)(cb + (((size_t)(unsigned)j0) << 2));
        int r1 = *(const int*)(cb + (((size_t)(unsigned)j1) << 2));
        int r2 = *(const int*)(cb + (((size_t)(unsigned)j2) << 2));
        unsigned c0 = (unsigned)((j0 < end0) ? r0 : 0);
        unsigned c1 = (unsigned)((j1 < end1) ? r1 : 0);
        unsigned c2 = (unsigned)((j2 < end2) ? r2 : 0);
        uint2 q0 = *(const uint2*)(Yb + ((size_t)c0 << 6) + lo);
        uint2 q1 = *(const uint2*)(Yb + ((size_t)c1 << 6) + lo);
        uint2 q2 = *(const uint2*)(Yb + ((size_t)c2 << 6) + lo);
        A00 += __builtin_amdgcn_cvt_pk_f32_fp8(q0.x, false);
        A01 += __builtin_amdgcn_cvt_pk_f32_fp8(q0.x, true);
        A02 += __builtin_amdgcn_cvt_pk_f32_fp8(q0.y, false);
        A03 += __builtin_amdgcn_cvt_pk_f32_fp8(q0.y, true);
        A10 += __builtin_amdgcn_cvt_pk_f32_fp8(q1.x, false);
        A11 += __builtin_amdgcn_cvt_pk_f32_fp8(q1.x, true);
        A12 += __builtin_amdgcn_cvt_pk_f32_fp8(q1.y, false);
        A13 += __builtin_amdgcn_cvt_pk_f32_fp8(q1.y, true);
        A20 += __builtin_amdgcn_cvt_pk_f32_fp8(q2.x, false);
        A21 += __builtin_amdgcn_cvt_pk_f32_fp8(q2.x, true);
        A22 += __builtin_amdgcn_cvt_pk_f32_fp8(q2.y, false);
        A23 += __builtin_amdgcn_cvt_pk_f32_fp8(q2.y, true);
        j0 += 8; j1 += 8; j2 += 8;
    }
    // butterfly each row's 8 partials down to one dim per lane
    float fins[3];
#pragma unroll
    for (int q = 0; q < 3; ++q) {
        f32x2 b0q, b1q, b2q, b3q;
        if (q == 0) { b0q = A00; b1q = A01; b2q = A02; b3q = A03; }
        else if (q == 1) { b0q = A10; b1q = A11; b2q = A12; b3q = A13; }
        else { b0q = A20; b1q = A21; b2q = A22; b3q = A23; }
        float acc[8] = {b0q.x, b0q.y, b1q.x, b1q.y,
                        b2q.x, b2q.y, b3q.x, b3q.y};
        bool gb0 = (g & 1) != 0;
        bool gb1 = (g & 2) != 0;
        bool gb2 = (g & 4) != 0;
        float s0 = gb0 ? acc[0] : acc[4];
        float s1 = gb0 ? acc[1] : acc[5];
        float s2 = gb0 ? acc[2] : acc[6];
        float s3 = gb0 ? acc[3] : acc[7];
        float a0f = (gb0 ? acc[4] : acc[0]) + __shfl_xor(s0, 8);
        float a1f = (gb0 ? acc[5] : acc[1]) + __shfl_xor(s1, 8);
        float a2f = (gb0 ? acc[6] : acc[2]) + __shfl_xor(s2, 8);
        float a3f = (gb0 ? acc[7] : acc[3]) + __shfl_xor(s3, 8);
        float t0 = gb1 ? a0f : a2f;
        float t1 = gb1 ? a1f : a3f;
        float c0f = (gb1 ? a2f : a0f) + __shfl_xor(t0, 16);
        float c1f = (gb1 ? a3f : a1f) + __shfl_xor(t1, 16);
        float uu = gb2 ? c0f : c1f;
        fins[q] = (gb2 ? c1f : c0f) + __shfl_xor(uu, 32);
    }
    float vals[3];
#pragma unroll
    for (int q = 0; q < 3; ++q) {
        int idx = idxs[q];
        float dr = dis[idx] * YINV;
        float iv = invd[idx] * YINV;
        const float* base0 = (q == 0) ? (ut + (size_t)u * 64)
                                      : (itb + (size_t)(idx - usernum) * 64);
        float x0v = base0[d];
        int b1 = (int)Y1[(size_t)idx * 64 + d];
        int b2 = (int)Y2[(size_t)idx * 64 + d];
        float y1v = __builtin_amdgcn_cvt_f32_fp8(b1, 0);
        float y2v = __builtin_amdgcn_cvt_f32_fp8(b2, 0);
        vals[q] = x0v + iv * (y1v + y2v) + fins[q] * dr;
    }
    float dp = vals[0] * vals[1];
    float dn = vals[0] * vals[2];
#pragma unroll
    for (int off = 1; off < 64; off <<= 1) {
        dp += __shfl_xor(dp, off);
        dn += __shfl_xor(dn, off);
    }
    if (lane == 0) {
        out[w]         = dp * 0.0625f;
        out[batch + w] = dn * 0.0625f;
    }
}

extern "C" void kernel_launch(void* const* d_in, const int* in_sizes, int n_in,
                              void* d_out, int out_size, void* d_ws,
                              size_t ws_size, hipStream_t stream) {
    const float* user_table = (const float*)d_in[0];
    const float* item_table = (const float*)d_in[1];
    const int*   rows       = (const int*)d_in[3];
    const int*   cols       = (const int*)d_in[4];
    const int*   user_ids   = (const int*)d_in[5];
    const int*   pos_seqs   = (const int*)d_in[6];
    const int*   neg_seqs   = (const int*)d_in[7];
    float*       out        = (float*)d_out;

    const int D = 64;
    int usernum = in_sizes[0] / D - 1;   // 100000
    int itemnum = in_sizes[1] / D - 1;   // 50000
    int nnz     = in_sizes[2];           // 4,000,000
    int batch   = in_sizes[5];           // 4096
    int n_nodes = usernum + itemnum + 1; // 150001
    int nb      = (n_nodes + (1 << NB_SHIFT) - 1) >> NB_SHIFT;  // 586
    int M       = nnz >> 1;              // 2,000,000 source pairs (mirror COO)

    // ---- workspace layout ----
    char* w = (char*)d_ws;
    auto alloc = [&](size_t bytes) {
        char* p = w;
        w += (bytes + 255) & ~(size_t)255;
        return p;
    };
    size_t ysz = (size_t)n_nodes * 64;          // 9.6 MB per fp8 Y buffer
    size_t tmp_sz = (size_t)nb * BCAP * 4;      // 37.5 MB partition scratch
    size_t slab_sz = tmp_sz > 3 * ysz ? tmp_sz : 3 * ysz;
    char* slab = alloc(slab_sz);
    // tmp aliases all three Y buffers: tmp is dead after finalize; Y0 is
    // first written by convert_y0 (after finalize), Y1/Y2 by the spmm layers.
    unsigned char* Y0 = (unsigned char*)slab;
    unsigned char* Y1 = (unsigned char*)(slab + ysz);
    unsigned char* Y2 = (unsigned char*)(slab + 2 * ysz);
    int* tmp = (int*)slab;
    int*   cv       = (int*)alloc((size_t)nnz * 4 + 8192);  // +pad: gather
                                      // loops may read cv past nnz; values
                                      // are masked before use as addresses
    int*   row_ptr  = (int*)alloc((size_t)(n_nodes + 1) * 4);
    float* dis      = (float*)alloc((size_t)n_nodes * 4);
    float* dis2     = (float*)alloc((size_t)n_nodes * 4);
    float* invd     = (float*)alloc((size_t)n_nodes * 4);
    int*   deg      = (int*)alloc((size_t)n_nodes * 4);
    int*   perm     = (int*)alloc((size_t)n_nodes * 4);
    // ctrl block (zeroed each launch): bcur[1024] | dhist[128] | dcur[128]
    int*   ctrl     = (int*)alloc(5120);
    int*   bcur     = ctrl;
    int*   dhist    = ctrl + 1024;
    int*   dcur     = ctrl + 1152;

    // ---- CSR build (bucket-staged; R8 showed global-atomic build is 25x
    //      slower) + degree histogram ----
    hipMemsetAsync(ctrl, 0, 5120, stream);
    int p1_tiles = (M + P1_SRC - 1) / P1_SRC;
    partition_kernel<<<p1_tiles, P1_DIM, 0, stream>>>(rows, cols, bcur, tmp,
                                                      M, nb);
    finalize_kernel<<<nb, 512, 0, stream>>>(tmp, bcur, row_ptr, dis, dis2,
                                            invd, cv, deg, dhist, n_nodes,
                                            nb, nnz);
    perm_kernel<<<nb, 256, 0, stream>>>(deg, dhist, dcur, perm, n_nodes);
    int conv_blocks = (n_nodes * 8 + 255) / 256;
    convert_y0_kernel<<<conv_blocks, 256, 0, stream>>>(
        (const float4*)user_table, (const float4*)item_table, dis,
        Y0, usernum, n_nodes);

    // ---- layers: Y0 -> Y1 -> Y2 (fp8 gather-sum + 1/deg scale) ----
    int spmm_grid = (n_nodes + 31) / 32;   // 32 perm-slots per 256-thr block
    spmm_y_kernel<<<spmm_grid, 256, 0, stream>>>(Y0, Y1, row_ptr, cv, dis2,
                                                 perm, n_nodes);
    spmm_y_kernel<<<spmm_grid, 256, 0, stream>>>(Y1, Y2, row_ptr, cv, dis2,
                                                 perm, n_nodes);

    // ---- fused layer-3 + gather + logits ----
    gather_logits_kernel<<<(batch + 3) / 4, 256, 0, stream>>>(
        user_table, item_table, Y1, Y2, row_ptr, cv, dis, invd, user_ids,
        pos_seqs, neg_seqs, out, usernum, itemnum, batch);
}

// Round 10
// 260.578 us; speedup vs baseline: 2.7277x; 2.3033x over previous
//
#include <hip/hip_runtime.h>
#include <hip/hip_fp16.h>
#include <cstdint>
#include <cstddef>

// ---------------------------------------------------------------------------
// LightGCN on MI355X — bucket-staged CSR build + fp8(e4m3) Y-scaled storage.
//   (R10 = exact revert to the R7 known-good state, 263.2 us measured.)
//   Y-substitution: Y_l = diag(deg^-1/2) X_l => Y_{l+1} = (1/deg)*sum Y_l[c]
//     -> SpMM inner loop is a pure gather-sum.
//   fp8 OCP e4m3 Y storage (64 B rows), scaled by S=4096 (values ~1e-3 sit
//     in e4m3 normal range; S rides through the linear recursion, divided
//     out in gather_logits). Measured: spmm FETCH = 92 MB = cv 16 + Y 76.8
//     (8-XCD compulsory floor), 43.8 us/layer, absmax 7e-7.
//   Atomic cost model locked in by R8/R9 failures:
//     - R8: per-edge global atomics w/ return + scattered dword stores =
//       240-350 us/kernel (25x slower than LDS-staged build).
//     - R9: 150K atomicAdds into a 128-word histogram serialize at the L2
//       line (~2.3 ns/op) = 351 us. NEVER funnel bulk atomics into few lines.
//   Build: LDS bucket-staged partition (>=1024-line-spread bounded global
//     atomics) + per-bucket finalize. gather_logits: 3 CSR row-sums in one
//     interleaved loop. 7 dispatches total.
// ---------------------------------------------------------------------------

typedef __attribute__((ext_vector_type(2))) float f32x2;

#define NB_SHIFT 8
#define BCAP 16000      // max edges per 256-row bucket (expected max ~10.7K)
#define P1_SRC 4096     // source pairs per tile -> 8192 directed edges
#define P1_DIM 512
#define YSCALE 4096.0f
#define YINV   (1.0f / 4096.0f)

// ---- partition mirror pairs into fixed-capacity bucket regions ----
__global__ __launch_bounds__(P1_DIM) void partition_kernel(
    const int* __restrict__ rows, const int* __restrict__ cols,
    int* __restrict__ bucket_cursor, int* __restrict__ tmp,
    int M /* = nnz/2 */, int nb) {
    __shared__ int            lhist[1024];
    __shared__ int            loff[1024];
    __shared__ int            ldelta[1024];   // dest_base[b] - loff[b]
    __shared__ int            wsum[8];
    __shared__ int            stage[2 * P1_SRC];   // 32 KB
    __shared__ unsigned short bstage[2 * P1_SRC];  // 16 KB
    int t = threadIdx.x;
    int lane = t & 63, wv = t >> 6;
    int base     = blockIdx.x * P1_SRC;
    int cnt_here = min(P1_SRC, M - base);
    int full4    = cnt_here >> 2;
    int rem      = cnt_here & 3;
    for (int i = t; i < 1024; i += P1_DIM) lhist[i] = 0;
    __syncthreads();
    const int4* rows4 = (const int4*)(rows + base);
    const int4* cols4 = (const int4*)(cols + base);
    int4 uu[2], vv[2];
    int  rka[8], rkb[8];
#pragma unroll
    for (int k = 0; k < 2; ++k) {
        int i4 = t + k * P1_DIM;
        if (i4 < full4) {
            uu[k] = rows4[i4];
            vv[k] = cols4[i4];
            int u4[4] = {uu[k].x, uu[k].y, uu[k].z, uu[k].w};
            int v4[4] = {vv[k].x, vv[k].y, vv[k].z, vv[k].w};
#pragma unroll
            for (int e = 0; e < 4; ++e) {
                rka[4 * k + e] = atomicAdd(&lhist[u4[e] >> NB_SHIFT], 1);
                rkb[4 * k + e] = atomicAdd(&lhist[v4[e] >> NB_SHIFT], 1);
            }
        }
    }
    int ur = 0, vr = 0, rkra = 0, rkrb = 0;
    bool has_rem = (t < rem);
    if (has_rem) {
        ur = rows[base + 4 * full4 + t];
        vr = cols[base + 4 * full4 + t];
        rkra = atomicAdd(&lhist[ur >> NB_SHIFT], 1);
        rkrb = atomicAdd(&lhist[vr >> NB_SHIFT], 1);
    }
    __syncthreads();
    // wave-shuffle exclusive scan over 1024 bucket counts (2 per thread)
    int v0 = lhist[2 * t], v1 = lhist[2 * t + 1];
    int ts = v0 + v1;
    int sc = ts;
#pragma unroll
    for (int off = 1; off < 64; off <<= 1) {
        int x = __shfl_up(sc, off);
        if (lane >= off) sc += x;
    }
    if (lane == 63) wsum[wv] = sc;
    __syncthreads();
    int prefix = 0;
#pragma unroll
    for (int k = 0; k < 8; ++k) {
        int s = wsum[k];
        prefix += (k < wv) ? s : 0;
    }
    int run = prefix + sc - ts;  // exclusive prefix of ts
    loff[2 * t]     = run;
    loff[2 * t + 1] = run + v0;
#pragma unroll
    for (int k = 0; k < 2; ++k) {
        int b  = 2 * t + k;
        int vvk = (k == 0) ? v0 : v1;
        if (b < nb && vvk > 0) {
            int old = atomicAdd(&bucket_cursor[b], vvk);   // delta in bucket
            ldelta[b] = b * BCAP + old - loff[b];
        }
    }
    __syncthreads();
#pragma unroll
    for (int k = 0; k < 2; ++k) {
        int i4 = t + k * P1_DIM;
        if (i4 < full4) {
            int u4[4] = {uu[k].x, uu[k].y, uu[k].z, uu[k].w};
            int v4[4] = {vv[k].x, vv[k].y, vv[k].z, vv[k].w};
#pragma unroll
            for (int e = 0; e < 4; ++e) {
                int ub = u4[e] >> NB_SHIFT;
                int s1 = loff[ub] + rka[4 * k + e];
                stage[s1]  = ((u4[e] & 255) << 18) | v4[e];
                bstage[s1] = (unsigned short)ub;
                int vb = v4[e] >> NB_SHIFT;
                int s2 = loff[vb] + rkb[4 * k + e];
                stage[s2]  = ((v4[e] & 255) << 18) | u4[e];
                bstage[s2] = (unsigned short)vb;
            }
        }
    }
    if (has_rem) {
        int ub = ur >> NB_SHIFT;
        int s1 = loff[ub] + rkra;
        stage[s1]  = ((ur & 255) << 18) | vr;
        bstage[s1] = (unsigned short)ub;
        int vb = vr >> NB_SHIFT;
        int s2 = loff[vb] + rkrb;
        stage[s2]  = ((vr & 255) << 18) | ur;
        bstage[s2] = (unsigned short)vb;
    }
    __syncthreads();
    int total = 2 * cnt_here;
    for (int s = t; s < total; s += P1_DIM) {
        tmp[s + ldelta[bstage[s]]] = stage[s];
    }
}

// ---- per-bucket finalize: self-prefix, row_ptr, dis/dis2/invd, cv ----
__global__ __launch_bounds__(512) void finalize_kernel(
    const int* __restrict__ tmp, const int* __restrict__ bcur,
    int* __restrict__ row_ptr, float* __restrict__ dis,
    float* __restrict__ dis2, float* __restrict__ invd,
    int* __restrict__ cv, int n_nodes, int nb, int nnz) {
    __shared__ int rcnt[256];
    __shared__ int ccur[256];   // global write cursor per row
    __shared__ int wsum[4];
    __shared__ int red[512];
    int b = blockIdx.x;
    int t = threadIdx.x;
    int lane = t & 63, wv = t >> 6;
    // exclusive prefix of bcur over buckets < b
    int partial = 0;
    for (int i = t; i < b; i += 512) partial += bcur[i];
    red[t] = partial;
    __syncthreads();
    for (int off = 256; off > 0; off >>= 1) {
        if (t < off) red[t] += red[t + off];
        __syncthreads();
    }
    int dbeg  = red[0];
    int count = bcur[b];
    int src   = b * BCAP;
    if (t < 256) rcnt[t] = 0;
    __syncthreads();
    for (int i = t; i < count; i += 512) {
        atomicAdd(&rcnt[tmp[src + i] >> 18], 1);
    }
    __syncthreads();
    // scan over 256 row counts (waves 0..3 fully active -> safe shuffles)
    int v = 0, sc = 0;
    if (t < 256) {
        v  = rcnt[t];
        sc = v;
#pragma unroll
        for (int off = 1; off < 64; off <<= 1) {
            int x = __shfl_up(sc, off);
            if (lane >= off) sc += x;
        }
        if (lane == 63) wsum[wv] = sc;
    }
    __syncthreads();
    if (t < 256) {
        int prefix = 0;
#pragma unroll
        for (int k = 0; k < 4; ++k) {
            int s = wsum[k];
            prefix += (k < wv) ? s : 0;
        }
        int ex = prefix + sc - v;
        ccur[t] = dbeg + ex;       // global cursor -> rank writes direct
        int row = (b << NB_SHIFT) + t;
        if (row < n_nodes) {
            row_ptr[row] = dbeg + ex;
            double dv = (double)v;
            dis[row]  = (v > 0) ? (float)(1.0 / sqrt(dv)) : 0.0f;
            dis2[row] = (v > 0) ? (float)(1.0 / dv) : 0.0f;
            invd[row] = (v > 0) ? (float)sqrt(dv) : 0.0f;
        }
    }
    if (b == nb - 1 && t == 0) row_ptr[n_nodes] = nnz;
    __syncthreads();
    // rank + direct cv write: dest window ~28KB -> L2 write-merge
    for (int i = t; i < count; i += 512) {
        int p  = tmp[src + i];
        int rk = atomicAdd(&ccur[p >> 18], 1);
        cv[rk] = p & 0x3FFFF;
    }
}

// ---- streaming Y0 convert: Y0[row] = fp8(S * dis[row] * X0[row]) ----
// 64 B rows; one uint2 (8 dims) per thread.
__global__ __launch_bounds__(256) void convert_y0_kernel(
    const float4* __restrict__ ut4, const float4* __restrict__ it4,
    const float* __restrict__ dis, unsigned char* __restrict__ Y0,
    int usernum, int n_nodes) {
    int idx = blockIdx.x * 256 + threadIdx.x;
    int row = idx >> 3;
    if (row >= n_nodes) return;
    int c = idx & 7;          // 8 dims per thread: dims [8c, 8c+8)
    float d = dis[row] * YSCALE;
    const float4* srcp = (row <= usernum)
        ? (ut4 + (size_t)row * 16 + 2 * c)
        : (it4 + (size_t)(row - usernum) * 16 + 2 * c);
    float4 a = srcp[0];
    float4 e = srcp[1];
    int w0 = 0, w1 = 0;
    w0 = __builtin_amdgcn_cvt_pk_fp8_f32(d * a.x, d * a.y, w0, false);
    w0 = __builtin_amdgcn_cvt_pk_fp8_f32(d * a.z, d * a.w, w0, true);
    w1 = __builtin_amdgcn_cvt_pk_fp8_f32(d * e.x, d * e.y, w1, false);
    w1 = __builtin_amdgcn_cvt_pk_fp8_f32(d * e.z, d * e.w, w1, true);
    uint2 o;
    o.x = (unsigned)w0;
    o.y = (unsigned)w1;
    *(uint2*)(Y0 + (size_t)row * 64 + c * 8) = o;
}

__device__ inline int lane_dim(int g, int l8) {
    return l8 * 8 + ((g & 1) * 4 + (g & 2) + (g >> 2));
}

// ---- SpMM over fp8 Y: 8 rows/wave, 8 lanes/row, 8 dims/lane (8 B) ----
// Y_{l+1}[r][d] = dis2[r] * sum_e Y_l[cv[e]][d]   (values scaled by YSCALE)
// 8-edge batches, trip count = wave-max degree, cv prefetch regs.
// Out-of-range slots gather row 0 (deg 0 => Y[0,:]==0, L1-hot).
// cv must be readable ~8KB past nnz (padded); values masked before use.
__global__ __launch_bounds__(256) void spmm_y_kernel(
    const unsigned char* __restrict__ Yin, unsigned char* __restrict__ Yout,
    const int* __restrict__ row_ptr, const int* __restrict__ cv,
    const float* __restrict__ dis2, int n_nodes) {
    int wid  = (blockIdx.x * blockDim.x + threadIdx.x) >> 6;
    int lane = threadIdx.x & 63;
    int g = lane >> 3, sub = lane & 7;
    int row = wid * 8 + g;
    bool ok = row < n_nodes;
    int beg = 0, end = 0;
    if (ok) {
        beg = row_ptr[row];
        end = row_ptr[row + 1];
    }
    float d2 = ok ? dis2[row] : 0.0f;
    const char* Yb = (const char*)Yin;
    const char* cb = (const char*)cv;
    unsigned lo = (unsigned)sub * 8u;
    f32x2 a0 = {0.f, 0.f}, a1 = {0.f, 0.f}, a2 = {0.f, 0.f}, a3 = {0.f, 0.f};
    // wave-max degree -> uniform trip count
    int mx = end - beg;
    mx = max(mx, __shfl_xor(mx, 8));
    mx = max(mx, __shfl_xor(mx, 16));
    mx = max(mx, __shfl_xor(mx, 32));
    int iters = (mx + 7) >> 3;
    int j = beg;
    size_t jb = ((size_t)(unsigned)j) << 2;
    int r0 = *(const int*)(cb + jb);
    int r1 = *(const int*)(cb + jb + 4u);
    int r2 = *(const int*)(cb + jb + 8u);
    int r3 = *(const int*)(cb + jb + 12u);
    int r4 = *(const int*)(cb + jb + 16u);
    int r5 = *(const int*)(cb + jb + 20u);
    int r6 = *(const int*)(cb + jb + 24u);
    int r7 = *(const int*)(cb + jb + 28u);
    for (int it = 0; it < iters; ++it) {
        unsigned c0 = (unsigned)((j     < end) ? r0 : 0);
        unsigned c1 = (unsigned)((j + 1 < end) ? r1 : 0);
        unsigned c2 = (unsigned)((j + 2 < end) ? r2 : 0);
        unsigned c3 = (unsigned)((j + 3 < end) ? r3 : 0);
        unsigned c4 = (unsigned)((j + 4 < end) ? r4 : 0);
        unsigned c5 = (unsigned)((j + 5 < end) ? r5 : 0);
        unsigned c6 = (unsigned)((j + 6 < end) ? r6 : 0);
        unsigned c7 = (unsigned)((j + 7 < end) ? r7 : 0);
        uint2 q0 = *(const uint2*)(Yb + ((size_t)c0 << 6) + lo);
        uint2 q1 = *(const uint2*)(Yb + ((size_t)c1 << 6) + lo);
        uint2 q2 = *(const uint2*)(Yb + ((size_t)c2 << 6) + lo);
        uint2 q3 = *(const uint2*)(Yb + ((size_t)c3 << 6) + lo);
        uint2 q4 = *(const uint2*)(Yb + ((size_t)c4 << 6) + lo);
        uint2 q5 = *(const uint2*)(Yb + ((size_t)c5 << 6) + lo);
        uint2 q6 = *(const uint2*)(Yb + ((size_t)c6 << 6) + lo);
        uint2 q7 = *(const uint2*)(Yb + ((size_t)c7 << 6) + lo);
        // prefetch next batch's indices (pad-safe past nnz; masked above)
        j += 8;
        jb = ((size_t)(unsigned)j) << 2;
        r0 = *(const int*)(cb + jb);
        r1 = *(const int*)(cb + jb + 4u);
        r2 = *(const int*)(cb + jb + 8u);
        r3 = *(const int*)(cb + jb + 12u);
        r4 = *(const int*)(cb + jb + 16u);
        r5 = *(const int*)(cb + jb + 20u);
        r6 = *(const int*)(cb + jb + 24u);
        r7 = *(const int*)(cb + jb + 28u);
        // HW fp8 decode (2 dims/cvt) + packed f32 adds
#define ACC_EDGE(q)                                                  \
        a0 += __builtin_amdgcn_cvt_pk_f32_fp8((q).x, false);         \
        a1 += __builtin_amdgcn_cvt_pk_f32_fp8((q).x, true);          \
        a2 += __builtin_amdgcn_cvt_pk_f32_fp8((q).y, false);         \
        a3 += __builtin_amdgcn_cvt_pk_f32_fp8((q).y, true);
        ACC_EDGE(q0) ACC_EDGE(q1) ACC_EDGE(q2) ACC_EDGE(q3)
        ACC_EDGE(q4) ACC_EDGE(q5) ACC_EDGE(q6) ACC_EDGE(q7)
#undef ACC_EDGE
    }
    if (ok) {
        int w0 = 0, w1 = 0;
        w0 = __builtin_amdgcn_cvt_pk_fp8_f32(a0.x * d2, a0.y * d2, w0, false);
        w0 = __builtin_amdgcn_cvt_pk_fp8_f32(a1.x * d2, a1.y * d2, w0, true);
        w1 = __builtin_amdgcn_cvt_pk_fp8_f32(a2.x * d2, a2.y * d2, w1, false);
        w1 = __builtin_amdgcn_cvt_pk_fp8_f32(a3.x * d2, a3.y * d2, w1, true);
        uint2 o;
        o.x = (unsigned)w0;
        o.y = (unsigned)w1;
        *(uint2*)(Yout + (size_t)row * 64 + lo) = o;
    }
}

// fused layer-3 + gather + logits: one wave per batch element.
// The 3 CSR row-sums (u, pos, neg) run in ONE interleaved loop —
// 3 gather chains overlap instead of concatenating. Exhausted rows gather
// row 0 (Y[0,:]==0, L1-hot). Trip count is wave-uniform (all lanes share w).
// emb(idx)[d] = X0fp32[idx][d] + invd*(Y1+Y2)[idx][d]/S + rowdot(Y2)[d]*dis/S
// out[b] = <emb(u), emb(pos)>/16; out[B+b] = <emb(u), emb(neg)>/16.
__global__ __launch_bounds__(256) void gather_logits_kernel(
    const float* __restrict__ ut, const float* __restrict__ itb,
    const unsigned char* __restrict__ Y1, const unsigned char* __restrict__ Y2,
    const int* __restrict__ row_ptr, const int* __restrict__ cv,
    const float* __restrict__ dis, const float* __restrict__ invd,
    const int* __restrict__ user_ids, const int* __restrict__ pos_seqs,
    const int* __restrict__ neg_seqs, float* __restrict__ out,
    int usernum, int itemnum, int batch) {
    int w    = (blockIdx.x * blockDim.x + threadIdx.x) >> 6;
    int lane = threadIdx.x & 63;
    if (w >= batch) return;
    int g = lane >> 3, l8 = lane & 7;
    int d = lane_dim(g, l8);
    int idxs[3];
    int u = min(max(user_ids[w], 0), usernum);
    idxs[0] = u;
    int p = min(max(pos_seqs[w], 1), itemnum);
    idxs[1] = usernum + p;
    int nn = min(max(neg_seqs[w], 1), itemnum);
    idxs[2] = usernum + nn;
    int beg0 = row_ptr[idxs[0]], end0 = row_ptr[idxs[0] + 1];
    int beg1 = row_ptr[idxs[1]], end1 = row_ptr[idxs[1] + 1];
    int beg2 = row_ptr[idxs[2]], end2 = row_ptr[idxs[2] + 1];
    int mx = max(end0 - beg0, max(end1 - beg1, end2 - beg2));
    int iters = (mx + 7) >> 3;
    const char* Yb = (const char*)Y2;
    const char* cb = (const char*)cv;
    unsigned lo = (unsigned)l8 * 8u;
    // 3 rows x 8-dim accumulators (f32x2 x4 each)
    f32x2 A00 = {0.f,0.f}, A01 = {0.f,0.f}, A02 = {0.f,0.f}, A03 = {0.f,0.f};
    f32x2 A10 = {0.f,0.f}, A11 = {0.f,0.f}, A12 = {0.f,0.f}, A13 = {0.f,0.f};
    f32x2 A20 = {0.f,0.f}, A21 = {0.f,0.f}, A22 = {0.f,0.f}, A23 = {0.f,0.f};
    int j0 = beg0 + g, j1 = beg1 + g, j2 = beg2 + g;
    for (int it = 0; it < iters; ++it) {
        // cv loads for all 3 rows (pad-safe past nnz; masked before gather)
        int r0 = *(const int*)(cb + (((size_t)(unsigned)j0) << 2));
        int r1 = *(const int*)(cb + (((size_t)(unsigned)j1) << 2));
        int r2 = *(const int*)(cb + (((size_t)(unsigned)j2) << 2));
        unsigned c0 = (unsigned)((j0 < end0) ? r0 : 0);
        unsigned c1 = (unsigned)((j1 < end1) ? r1 : 0);
        unsigned c2 = (unsigned)((j2 < end2) ? r2 : 0);
        uint2 q0 = *(const uint2*)(Yb + ((size_t)c0 << 6) + lo);
        uint2 q1 = *(const uint2*)(Yb + ((size_t)c1 << 6) + lo);
        uint2 q2 = *(const uint2*)(Yb + ((size_t)c2 << 6) + lo);
        A00 += __builtin_amdgcn_cvt_pk_f32_fp8(q0.x, false);
        A01 += __builtin_amdgcn_cvt_pk_f32_fp8(q0.x, true);
        A02 += __builtin_amdgcn_cvt_pk_f32_fp8(q0.y, false);
        A03 += __builtin_amdgcn_cvt_pk_f32_fp8(q0.y, true);
        A10 += __builtin_amdgcn_cvt_pk_f32_fp8(q1.x, false);
        A11 += __builtin_amdgcn_cvt_pk_f32_fp8(q1.x, true);
        A12 += __builtin_amdgcn_cvt_pk_f32_fp8(q1.y, false);
        A13 += __builtin_amdgcn_cvt_pk_f32_fp8(q1.y, true);
        A20 += __builtin_amdgcn_cvt_pk_f32_fp8(q2.x, false);
        A21 += __builtin_amdgcn_cvt_pk_f32_fp8(q2.x, true);
        A22 += __builtin_amdgcn_cvt_pk_f32_fp8(q2.y, false);
        A23 += __builtin_amdgcn_cvt_pk_f32_fp8(q2.y, true);
        j0 += 8; j1 += 8; j2 += 8;
    }
    // butterfly each row's 8 partials down to one dim per lane
    float fins[3];
#pragma unroll
    for (int q = 0; q < 3; ++q) {
        f32x2 b0q, b1q, b2q, b3q;
        if (q == 0) { b0q = A00; b1q = A01; b2q = A02; b3q = A03; }
        else if (q == 1) { b0q = A10; b1q = A11; b2q = A12; b3q = A13; }
        else { b0q = A20; b1q = A21; b2q = A22; b3q = A23; }
        float acc[8] = {b0q.x, b0q.y, b1q.x, b1q.y,
                        b2q.x, b2q.y, b3q.x, b3q.y};
        bool gb0 = (g & 1) != 0;
        bool gb1 = (g & 2) != 0;
        bool gb2 = (g & 4) != 0;
        float s0 = gb0 ? acc[0] : acc[4];
        float s1 = gb0 ? acc[1] : acc[5];
        float s2 = gb0 ? acc[2] : acc[6];
        float s3 = gb0 ? acc[3] : acc[7];
        float a0f = (gb0 ? acc[4] : acc[0]) + __shfl_xor(s0, 8);
        float a1f = (gb0 ? acc[5] : acc[1]) + __shfl_xor(s1, 8);
        float a2f = (gb0 ? acc[6] : acc[2]) + __shfl_xor(s2, 8);
        float a3f = (gb0 ? acc[7] : acc[3]) + __shfl_xor(s3, 8);
        float t0 = gb1 ? a0f : a2f;
        float t1 = gb1 ? a1f : a3f;
        float c0f = (gb1 ? a2f : a0f) + __shfl_xor(t0, 16);
        float c1f = (gb1 ? a3f : a1f) + __shfl_xor(t1, 16);
        float uu = gb2 ? c0f : c1f;
        fins[q] = (gb2 ? c1f : c0f) + __shfl_xor(uu, 32);
    }
    float vals[3];
#pragma unroll
    for (int q = 0; q < 3; ++q) {
        int idx = idxs[q];
        float dr = dis[idx] * YINV;
        float iv = invd[idx] * YINV;
        const float* base0 = (q == 0) ? (ut + (size_t)u * 64)
                                      : (itb + (size_t)(idx - usernum) * 64);
        float x0v = base0[d];
        int b1 = (int)Y1[(size_t)idx * 64 + d];
        int b2 = (int)Y2[(size_t)idx * 64 + d];
        float y1v = __builtin_amdgcn_cvt_f32_fp8(b1, 0);
        float y2v = __builtin_amdgcn_cvt_f32_fp8(b2, 0);
        vals[q] = x0v + iv * (y1v + y2v) + fins[q] * dr;
    }
    float dp = vals[0] * vals[1];
    float dn = vals[0] * vals[2];
#pragma unroll
    for (int off = 1; off < 64; off <<= 1) {
        dp += __shfl_xor(dp, off);
        dn += __shfl_xor(dn, off);
    }
    if (lane == 0) {
        out[w]         = dp * 0.0625f;
        out[batch + w] = dn * 0.0625f;
    }
}

extern "C" void kernel_launch(void* const* d_in, const int* in_sizes, int n_in,
                              void* d_out, int out_size, void* d_ws,
                              size_t ws_size, hipStream_t stream) {
    const float* user_table = (const float*)d_in[0];
    const float* item_table = (const float*)d_in[1];
    const int*   rows       = (const int*)d_in[3];
    const int*   cols       = (const int*)d_in[4];
    const int*   user_ids   = (const int*)d_in[5];
    const int*   pos_seqs   = (const int*)d_in[6];
    const int*   neg_seqs   = (const int*)d_in[7];
    float*       out        = (float*)d_out;

    const int D = 64;
    int usernum = in_sizes[0] / D - 1;   // 100000
    int itemnum = in_sizes[1] / D - 1;   // 50000
    int nnz     = in_sizes[2];           // 4,000,000
    int batch   = in_sizes[5];           // 4096
    int n_nodes = usernum + itemnum + 1; // 150001
    int nb      = (n_nodes + (1 << NB_SHIFT) - 1) >> NB_SHIFT;  // 586
    int M       = nnz >> 1;              // 2,000,000 source pairs (mirror COO)

    // ---- workspace layout ----
    char* w = (char*)d_ws;
    auto alloc = [&](size_t bytes) {
        char* p = w;
        w += (bytes + 255) & ~(size_t)255;
        return p;
    };
    size_t ysz = (size_t)n_nodes * 64;          // 9.6 MB per fp8 Y buffer
    size_t tmp_sz = (size_t)nb * BCAP * 4;      // 37.5 MB partition scratch
    size_t slab_sz = tmp_sz > 3 * ysz ? tmp_sz : 3 * ysz;
    char* slab = alloc(slab_sz);
    // tmp aliases all three Y buffers: tmp is dead after finalize; Y0 is
    // first written by convert_y0 (after finalize), Y1/Y2 by the spmm layers.
    unsigned char* Y0 = (unsigned char*)slab;
    unsigned char* Y1 = (unsigned char*)(slab + ysz);
    unsigned char* Y2 = (unsigned char*)(slab + 2 * ysz);
    int* tmp = (int*)slab;
    int*   cv       = (int*)alloc((size_t)nnz * 4 + 8192);  // +pad: gather
                                      // loops may read cv past nnz; values
                                      // are masked before use as addresses
    int*   row_ptr  = (int*)alloc((size_t)(n_nodes + 1) * 4);
    float* dis      = (float*)alloc((size_t)n_nodes * 4);
    float* dis2     = (float*)alloc((size_t)n_nodes * 4);
    float* invd     = (float*)alloc((size_t)n_nodes * 4);
    int*   bcur     = (int*)alloc(4096);

    // ---- CSR build (bucket-staged; R8/R9 showed global-atomic variants
    //      are 6-25x slower) ----
    hipMemsetAsync(bcur, 0, 4096, stream);
    int p1_tiles = (M + P1_SRC - 1) / P1_SRC;
    partition_kernel<<<p1_tiles, P1_DIM, 0, stream>>>(rows, cols, bcur, tmp,
                                                      M, nb);
    finalize_kernel<<<nb, 512, 0, stream>>>(tmp, bcur, row_ptr, dis, dis2,
                                            invd, cv, n_nodes, nb, nnz);
    int conv_blocks = (n_nodes * 8 + 255) / 256;
    convert_y0_kernel<<<conv_blocks, 256, 0, stream>>>(
        (const float4*)user_table, (const float4*)item_table, dis,
        Y0, usernum, n_nodes);

    // ---- layers: Y0 -> Y1 -> Y2 (fp8 gather-sum + 1/deg scale) ----
    int spmm_grid = (n_nodes + 31) / 32;   // 32 rows per 256-thr block
    spmm_y_kernel<<<spmm_grid, 256, 0, stream>>>(Y0, Y1, row_ptr, cv, dis2,
                                                 n_nodes);
    spmm_y_kernel<<<spmm_grid, 256, 0, stream>>>(Y1, Y2, row_ptr, cv, dis2,
                                                 n_nodes);

    // ---- fused layer-3 + gather + logits ----
    gather_logits_kernel<<<(batch + 3) / 4, 256, 0, stream>>>(
        user_table, item_table, Y1, Y2, row_ptr, cv, dis, invd, user_ids,
        pos_seqs, neg_seqs, out, usernum, itemnum, batch);
}